// Round 14
// baseline (168.066 us; speedup 1.0000x reference)
//
#include <hip/hip_runtime.h>
#include <hip/hip_bf16.h>

#define B_   512
#define C_   256
#define N_   81                 // tokens per batch (9x9)
#define M_   (B_ * N_)          // 41472
#define KNN  9

typedef __attribute__((ext_vector_type(8))) short short8;
typedef __attribute__((ext_vector_type(4))) float f32x4;
typedef __attribute__((ext_vector_type(4))) ushort u16x4;

#define GLD16(g, l) __builtin_amdgcn_global_load_lds(                      \
    (const __attribute__((address_space(1))) void*)(g),                    \
    (__attribute__((address_space(3))) void*)(l), 16, 0, 0)

__device__ __forceinline__ float bf2f(ushort u) {
  union { uint i; float f; } c; c.i = (uint)u << 16; return c.f;
}
__device__ __forceinline__ ushort f2bf(float f) {
  __hip_bfloat16 h = __float2bfloat16(f); return *(ushort*)&h;
}

// ---------------------------------------------------------------- kernel A1
// blocks 0..4095: transpose/split per (batch, 32-ch chunk) -> tokb hi rows
// (linear [m][256] bf16) + lobuf lo image (6144 B per (b,ch), pre-swizzled).
// blocks 4096..4863: weight pack (wq|wk|wv -> bf16 wcat, biases -> bcat).
__global__ __launch_bounds__(256) void split_kernel(
    const float* __restrict__ x, ushort* __restrict__ tokb,
    char* __restrict__ lobuf,
    const float* __restrict__ wq, const float* __restrict__ bq,
    const float* __restrict__ wk, const float* __restrict__ bk,
    const float* __restrict__ wv, const float* __restrict__ bv,
    ushort* __restrict__ wcat, float* __restrict__ bcat) {
  __shared__ __align__(16) float raw[32 * 81];   // 10368 B
  const int bid = blockIdx.x;
  const int tid = threadIdx.x;
  if (bid >= 4096) {             // ---- weight pack path
    const int j = bid - 4096, c = tid;
    const int sel = j >> 8, jr = j & 255;
    const float* W  = sel == 0 ? wq : (sel == 1 ? wk : wv);
    const float* Bb = sel == 0 ? bq : (sel == 1 ? bk : bv);
    wcat[(size_t)j * 256 + c] = f2bf(W[jr * 256 + c]);
    if (c == 0) bcat[j] = Bb[jr];
    return;
  }
  const int b = bid >> 3, ch = bid & 7;
  const float* src = x + (size_t)b * (C_ * N_) + ch * 32 * N_;
#pragma unroll
  for (int it = 0; it < 3; ++it) {
    int e4 = tid + it * 256;
    if (e4 < 648) *(f32x4*)&raw[e4 * 4] = *(const f32x4*)&src[e4 * 4];
  }
  char* dst = lobuf + (size_t)bid * 6144;
  __syncthreads();
#pragma unroll
  for (int it = 0; it < 6; ++it) {
    int p = tid + it * 256;
    if (p < 1296) {
      int n = p >> 4, q = p & 15;
      float v0 = raw[(2 * q) * N_ + n];
      float v1 = raw[(2 * q + 1) * N_ + n];
      __hip_bfloat16 h0 = __float2bfloat16(v0);
      __hip_bfloat16 h1 = __float2bfloat16(v1);
      float r0 = v0 - __bfloat162float(h0);
      float r1 = v1 - __bfloat162float(h1);
      __hip_bfloat16 g0 = __float2bfloat16(r0);
      __hip_bfloat16 g1 = __float2bfloat16(r1);
      uint hp = (uint)(*(ushort*)&h0) | ((uint)(*(ushort*)&h1) << 16);
      uint lp = (uint)(*(ushort*)&g0) | ((uint)(*(ushort*)&g1) << 16);
      int off = (((q >> 2) << 4) ^ (((n >> 1) & 3) << 4)) + ((q & 3) << 2);
      *(uint*)(dst + n * 64 + off) = lp;
      *(uint*)&tokb[((size_t)(b * N_ + n)) * 256 + ch * 32 + 2 * q] = hp;
    }
  }
}

// ---------------------------------------------------------------- kernel A2
// Per batch: double-buffered staging (counted vmcnt(3)); HI staged from tokb
// with pre-swizzled per-lane source, LO from lobuf linearly. 4-term MFMA
// gram, diag from G, 9-smallest selection. (verified r12-r13, bit-exact)
__global__ __launch_bounds__(256) void knn_kernel(
    const ushort* __restrict__ tokb, const char* __restrict__ lobuf,
    int* __restrict__ knn_idx) {
  __shared__ __align__(16) char smem[31488];     // bufs 2x(HI 6144|LO 6144)
  __shared__ float sqv[96];
  const int b = blockIdx.x;
  const int tid = threadIdx.x;
  const int w = tid >> 6, lane = tid & 63;
  const int wr = w >> 1, wc = w & 1;              // 48x48 quadrant of G
  const int l15 = lane & 15;
  const int g16 = lane >> 4;                      // 16B k-group 0..3

  const char* tb = (const char*)(tokb + (size_t)b * N_ * 256);  // 81 x 512B
  const char* lb = lobuf + (size_t)b * 8 * 6144;

#pragma unroll
  for (int it = 0; it < 3; ++it) {
    int idx = it * 256 + tid;
    if (idx < 384) {
      int n = idx >> 2, gp = idx & 3;
      int g = gp ^ ((n >> 1) & 3);
      GLD16(tb + (size_t)n * 512 + (g << 4), smem + idx * 16);
    } else {
      GLD16(lb + (idx - 384) * 16, smem + idx * 16);
    }
  }

  f32x4 acc[3][3];
#pragma unroll
  for (int i = 0; i < 3; ++i)
#pragma unroll
    for (int j = 0; j < 3; ++j) acc[i][j] = {0.f, 0.f, 0.f, 0.f};

#pragma unroll
  for (int ch = 0; ch < 8; ++ch) {
    char* cur = smem + (ch & 1) * 12288;
    char* nxt = smem + ((ch + 1) & 1) * 12288;
    if (ch < 7) {
#pragma unroll
      for (int it = 0; it < 3; ++it) {
        int idx = it * 256 + tid;
        if (idx < 384) {
          int n = idx >> 2, gp = idx & 3;
          int g = gp ^ ((n >> 1) & 3);
          GLD16(tb + (size_t)n * 512 + (ch + 1) * 64 + (g << 4),
                nxt + idx * 16);
        } else {
          GLD16(lb + (size_t)(ch + 1) * 6144 + (idx - 384) * 16,
                nxt + idx * 16);
        }
      }
      asm volatile("s_waitcnt vmcnt(3)" ::: "memory");   // cur's 3 done
    } else {
      asm volatile("s_waitcnt vmcnt(0)" ::: "memory");
    }
    __builtin_amdgcn_s_barrier();
    __builtin_amdgcn_sched_barrier(0);
    short8 ah[3], al[3], bh[3], bl[3];
#pragma unroll
    for (int i = 0; i < 3; ++i) {
      int ra = wr * 48 + i * 16 + l15;
      int oa = ra * 64 + ((g16 << 4) ^ (((ra >> 1) & 3) << 4));
      ah[i] = *(const short8*)(cur + oa);
      al[i] = *(const short8*)(cur + 6144 + oa);
      int rb = wc * 48 + i * 16 + l15;
      int ob = rb * 64 + ((g16 << 4) ^ (((rb >> 1) & 3) << 4));
      bh[i] = *(const short8*)(cur + ob);
      bl[i] = *(const short8*)(cur + 6144 + ob);
    }
#pragma unroll
    for (int i = 0; i < 3; ++i)
#pragma unroll
      for (int j = 0; j < 3; ++j) {
        acc[i][j] = __builtin_amdgcn_mfma_f32_16x16x32_bf16(
            ah[i], bh[j], acc[i][j], 0, 0, 0);
        acc[i][j] = __builtin_amdgcn_mfma_f32_16x16x32_bf16(
            ah[i], bl[j], acc[i][j], 0, 0, 0);
        acc[i][j] = __builtin_amdgcn_mfma_f32_16x16x32_bf16(
            al[i], bh[j], acc[i][j], 0, 0, 0);
        acc[i][j] = __builtin_amdgcn_mfma_f32_16x16x32_bf16(
            al[i], bl[j], acc[i][j], 0, 0, 0);
      }
    __builtin_amdgcn_sched_barrier(0);
    __builtin_amdgcn_s_barrier();   // reads done before next GLD overwrite
  }
  float* G = (float*)smem;
#pragma unroll
  for (int i = 0; i < 3; ++i) {
    const int row0 = wr * 48 + i * 16 + ((lane >> 4) << 2);
#pragma unroll
    for (int j = 0; j < 3; ++j) {
      const int col = wc * 48 + j * 16 + l15;
#pragma unroll
      for (int reg = 0; reg < 4; ++reg) {
        const int row = row0 + reg;
        if (row < N_) G[row * 97 + col] = acc[i][j][reg];
      }
    }
  }
  __syncthreads();
  if (tid < N_) sqv[tid] = G[tid * 97 + tid];   // diag = |token|^2 (4-term)
  __syncthreads();
  if (tid < N_) {
    const int n = tid;
    const float sn = sqv[n];
    const float* grow = &G[n * 97];
    float bd[KNN]; int bi[KNN];
#pragma unroll
    for (int k = 0; k < KNN; ++k) { bd[k] = 3.4e38f; bi[k] = 0; }
    for (int m = 0; m < N_; ++m) {
      float d2 = sn + sqv[m] - 2.f * grow[m];
      float wv = bd[0]; int wi = 0;
#pragma unroll
      for (int k = 1; k < KNN; ++k) {
        bool g_ = bd[k] > wv;
        wv = g_ ? bd[k] : wv;
        wi = g_ ? k : wi;
      }
      bool repl = d2 < wv;
#pragma unroll
      for (int k = 0; k < KNN; ++k) {
        bool here = repl & (wi == k);
        bd[k] = here ? d2 : bd[k];
        bi[k] = here ? m : bi[k];
      }
    }
#pragma unroll
    for (int k = 0; k < KNN; ++k)
      knn_idx[((size_t)b * N_ + n) * KNN + k] = bi[k];
  }
}

// ---------------------------------------------------------------- kernel B
// bf16 MFMA GEMM: qkvb[M][768] = tok[M][256] @ wcat^T + bcat (bf16 out).
// XCD-chunked, jt-inner 1D grid (A-tile L2 reuse, verified r12).
__global__ __launch_bounds__(256) void qkv_mfma_kernel(
    const ushort* __restrict__ tokb, const ushort* __restrict__ wcat,
    const float* __restrict__ bcat, ushort* __restrict__ qkvb) {
  __shared__ ushort At[128 * 64];   // 16 KB, row-major [r][k], swizzled
  __shared__ ushort Bt[128 * 64];   // 16 KB
  const int bid = blockIdx.x;       // grid 1968 = 8 * 41 * 6
  const int xcd = bid & 7, li = bid >> 3;      // li 0..245
  const int mt = xcd * 41 + li / 6;            // m-tile 0..327
  if (mt >= 324) return;                       // 24 pad blocks exit
  const int m0 = mt * 128;
  const int j0 = (li % 6) * 128;
  const int tid = threadIdx.x;
  const int w = tid >> 6, lane = tid & 63;
  const int wr = w >> 1, wc = w & 1;

  const char* pA[4]; const char* pB[4]; int oL[4];
#pragma unroll
  for (int it = 0; it < 4; ++it) {
    int o = (it * 256 + tid) * 16;
    int r = o >> 7, cp = o & 127;
    int cl = cp ^ ((r & 7) << 4);
    oL[it] = o;
    pA[it] = (const char*)tokb + ((size_t)(m0 + r) * 256) * 2 + cl;
    pB[it] = (const char*)wcat + ((size_t)(j0 + r) * 256) * 2 + cl;
  }

  f32x4 acc[4][4];
#pragma unroll
  for (int i = 0; i < 4; ++i)
#pragma unroll
    for (int j = 0; j < 4; ++j) acc[i][j] = {0.f, 0.f, 0.f, 0.f};

  const int l15 = lane & 15;
  const int sw = (lane & 7) << 4;
  const int kgrp = (lane >> 4) << 4;

  for (int k0 = 0; k0 < 256; k0 += 64) {
    __syncthreads();
#pragma unroll
    for (int it = 0; it < 4; ++it) {
      GLD16(pA[it] + k0 * 2, (char*)At + oL[it]);
      GLD16(pB[it] + k0 * 2, (char*)Bt + oL[it]);
    }
    __syncthreads();
#pragma unroll
    for (int kk = 0; kk < 2; ++kk) {
      const int cb = (kk * 64 + kgrp) ^ sw;
      short8 am[4], bn[4];
#pragma unroll
      for (int i = 0; i < 4; ++i) {
        const int ra = wr * 64 + i * 16 + l15;
        am[i] = *(const short8*)((const char*)At + ra * 128 + cb);
        const int rb = wc * 64 + i * 16 + l15;
        bn[i] = *(const short8*)((const char*)Bt + rb * 128 + cb);
      }
#pragma unroll
      for (int i = 0; i < 4; ++i)
#pragma unroll
        for (int j = 0; j < 4; ++j)
          acc[i][j] = __builtin_amdgcn_mfma_f32_16x16x32_bf16(
              am[i], bn[j], acc[i][j], 0, 0, 0);
    }
  }

  // epilogue -> bf16 qkv
#pragma unroll
  for (int j = 0; j < 4; ++j) {
    const int colj = j0 + wc * 64 + j * 16 + l15;
    const float bs = bcat[colj];
#pragma unroll
    for (int i = 0; i < 4; ++i) {
      const int rowm = m0 + wr * 64 + i * 16 + ((lane >> 4) << 2);
#pragma unroll
      for (int reg = 0; reg < 4; ++reg)
        qkvb[(size_t)(rowm + reg) * 768 + colj] = f2bf(acc[i][j][reg] + bs);
    }
  }
}

// ---------------------------------------------------------------- kernel C
// Per-batch attention + BN partials. 512 blocks x 1024 threads (16 waves,
// 2 blocks/CU = full 32 waves/CU). Wave w handles tokens w+16r (r=0..5)
// with the r13-verbatim per-token code (bit-identical outputs). Output ->
// compact outNC[m][256] (coalesced) + LDS obuf; after barrier the block
// computes its batch's BN partial sums from LDS (fixed order, deterministic)
// -> ps[b][256]. Replaces attn_kernel + bn_partial_kernel.
__global__ __launch_bounds__(1024) void attn_bn_kernel(
    const ushort* __restrict__ qkvc, const int* __restrict__ knn_idx,
    const float* __restrict__ a, ushort* __restrict__ outNC,
    float* __restrict__ ps, float* __restrict__ ps2) {
  __shared__ __align__(16) char obuf[N_ * 512];   // 41472 B bf16 [81][256]
  __shared__ float psl[2][256], psl2[2][256];
  const int bid = blockIdx.x;
  const int b = (bid & 7) * 64 + (bid >> 3);      // XCD-bijective swizzle
  const int tid = threadIdx.x;
  const int w = tid >> 6, lane = tid & 63;
  const int bbase = b * N_;
  const f32x4 a4 = *(const f32x4*)&a[lane * 4];

  for (int r = 0; r < 6; ++r) {
    const int tok = w + 16 * r;
    if (tok < N_) {
      const int m = bbase + tok;
      int nbk_l = 0;
      if (lane < KNN) nbk_l = knn_idx[(size_t)m * KNN + lane];

      const u16x4 qu = *(const u16x4*)&qkvc[(size_t)m * 768 + lane * 4];
      float q4[4];
#pragma unroll
      for (int u = 0; u < 4; ++u) q4[u] = bf2f(qu[u]);

      float sc[KNN];
      int nb[KNN];
#pragma unroll
      for (int k = 0; k < KNN; ++k) {
        const int nbk = __builtin_amdgcn_readlane(nbk_l, k);
        nb[k] = nbk;
        const ushort* krow = qkvc + (size_t)(bbase + nbk) * 768 + 256;
        const u16x4 ku = *(const u16x4*)&krow[lane * 4];
        float p = 0.f;
#pragma unroll
        for (int u = 0; u < 4; ++u) {
          float t = q4[u] + bf2f(ku[u]);
          t = fmaxf(t, 0.2f * t);              // leaky_relu(t, 0.2)
          p = __builtin_fmaf(t, a4[u], p);
        }
        p += __shfl_xor(p, 1, 16);
        p += __shfl_xor(p, 2, 16);
        p += __shfl_xor(p, 4, 16);
        p += __shfl_xor(p, 8, 16);
        sc[k] = p;
      }
      float mx = sc[0];
#pragma unroll
      for (int k = 1; k < KNN; ++k) mx = fmaxf(mx, sc[k]);
      float s = 0.f;
#pragma unroll
      for (int k = 0; k < KNN; ++k) {
        sc[k] = __builtin_amdgcn_exp2f((sc[k] - mx) * 1.44269504f);
        s += sc[k];
      }
      const float inv = __builtin_amdgcn_rcpf(s);
      f32x4 acc = {0.f, 0.f, 0.f, 0.f};
#pragma unroll
      for (int k = 0; k < KNN; ++k) {
        const ushort* vrow = qkvc + (size_t)(bbase + nb[k]) * 768 + 512;
        const u16x4 vu = *(const u16x4*)&vrow[lane * 4];
        const float wk_ = sc[k] * inv;
#pragma unroll
        for (int u = 0; u < 4; ++u)
          acc[u] = __builtin_fmaf(wk_, bf2f(vu[u]), acc[u]);
      }
      u16x4 o;
#pragma unroll
      for (int u = 0; u < 4; ++u) o[u] = f2bf(acc[u]);
      *(u16x4*)(obuf + tok * 512 + lane * 8) = o;
      *(u16x4*)&outNC[(size_t)m * 256 + lane * 4] = o;
    }
  }
  __syncthreads();
  // BN partials from LDS (2-way bank aliasing on the column read = free)
  if (tid < 512) {
    const int half = tid >> 8, c = tid & 255;
    const int rbeg = half * 41, rend = half ? 81 : 41;
    float s = 0.f, s2 = 0.f;
    for (int rr = rbeg; rr < rend; ++rr) {
      float v = bf2f(*(const ushort*)(obuf + rr * 512 + c * 2));
      s += v; s2 = __builtin_fmaf(v, v, s2);
    }
    psl[half][c] = s;
    psl2[half][c] = s2;
  }
  __syncthreads();
  if (tid < 256) {
    ps[b * 256 + tid] = psl[0][tid] + psl[1][tid];
    ps2[b * 256 + tid] = psl2[0][tid] + psl2[1][tid];
  }
}

// ---------------------------------------------------------------- kernel D2
__global__ __launch_bounds__(256) void bn_finalize_kernel(
    const float* __restrict__ ps, const float* __restrict__ ps2,
    const float* __restrict__ gamma, const float* __restrict__ beta,
    float* __restrict__ scale, float* __restrict__ shift) {
  const int c = threadIdx.x;
  float s = 0.f, s2 = 0.f;
  for (int g = 0; g < 512; ++g) { s += ps[g * 256 + c]; s2 += ps2[g * 256 + c]; }
  const float mean = s * (1.f / (float)M_);
  const float var = s2 * (1.f / (float)M_) - mean * mean;
  const float rstd = rsqrtf(var + 1e-5f);
  scale[c] = gamma[c] * rstd;
  shift[c] = beta[c] - mean * gamma[c] * rstd;
}

// ---------------------------------------------------------------- kernel E
// y = relu(outNC*scale + shift + x), transposed back to [B][C][81] via LDS.
__global__ __launch_bounds__(256) void bn_apply_kernel(
    const ushort* __restrict__ outNC, const float* __restrict__ x,
    const float* __restrict__ scale, const float* __restrict__ shift,
    float* __restrict__ y) {
  __shared__ float t[N_ * 65];
  const int b = blockIdx.x, tid = threadIdx.x;
  for (int c0 = 0; c0 < 256; c0 += 64) {
    __syncthreads();
    for (int e = tid; e < N_ * 64; e += 256) {
      int n = e >> 6, c = e & 63;
      t[n * 65 + c] = bf2f(outNC[((size_t)b * N_ + n) * 256 + c0 + c]);
    }
    __syncthreads();
    for (int f = tid; f < 64 * N_; f += 256) {
      int c = f / N_, n = f - c * N_;
      float o = t[n * 65 + c];
      size_t gi = (size_t)b * (C_ * N_) + (size_t)(c0 + c) * N_ + n;
      float bn = o * scale[c0 + c] + shift[c0 + c];
      float v = bn + x[gi];
      y[gi] = v > 0.f ? v : 0.f;
    }
  }
}

// ----------------------------------------------------------------
extern "C" void kernel_launch(void* const* d_in, const int* in_sizes, int n_in,
                              void* d_out, int out_size, void* d_ws,
                              size_t ws_size, hipStream_t stream) {
  const float* x     = (const float*)d_in[0];
  const float* wq    = (const float*)d_in[1];
  const float* bq    = (const float*)d_in[2];
  const float* wk    = (const float*)d_in[3];
  const float* bk    = (const float*)d_in[4];
  const float* wv    = (const float*)d_in[5];
  const float* bv    = (const float*)d_in[6];
  const float* a     = (const float*)d_in[7];
  const float* gamma = (const float*)d_in[8];
  const float* beta  = (const float*)d_in[9];
  float* out = (float*)d_out;

  ushort* qkvb = (ushort*)d_ws;                         // M*768 bf16 (63.7MB)
  char*   lobuf = (char*)qkvb;                          // 25.2 MB alias,
                                                        // consumed pre-qkv
  ushort* tokb = qkvb + (size_t)M_ * 768;               // M*256 bf16
  ushort* wcat = tokb + (size_t)M_ * 256;               // 768*256 bf16
  float*  bcat = (float*)(wcat + 768 * 256);            // 768 f32
  int*    kidx = (int*)(bcat + 768);                    // M*9 int
  float*  ps   = (float*)(kidx + (size_t)M_ * KNN);     // 512*256
  float*  ps2  = ps + 512 * 256;                        // 512*256
  float*  scale = ps2 + 512 * 256;                      // 256
  float*  shift = scale + 256;                          // 256
  ushort* outNC = (ushort*)(shift + 256);               // M*256 bf16 (21.2MB)

  split_kernel<<<4096 + 768, 256, 0, stream>>>(
      x, tokb, lobuf, wq, bq, wk, bk, wv, bv, wcat, bcat);
  knn_kernel<<<B_, 256, 0, stream>>>(tokb, lobuf, kidx);
  qkv_mfma_kernel<<<1968, 256, 0, stream>>>(tokb, wcat, bcat, qkvb);
  attn_bn_kernel<<<B_, 1024, 0, stream>>>(qkvb, kidx, a, outNC, ps, ps2);
  bn_finalize_kernel<<<1, 256, 0, stream>>>(ps, ps2, gamma, beta, scale, shift);
  bn_apply_kernel<<<B_, 256, 0, stream>>>(outNC, x, scale, shift, out);
}

// Round 15
// 159.139 us; speedup vs baseline: 1.0561x; 1.0561x over previous
//
#include <hip/hip_runtime.h>
#include <hip/hip_bf16.h>

#define B_   512
#define C_   256
#define N_   81                 // tokens per batch (9x9)
#define M_   (B_ * N_)          // 41472
#define KNN  9

typedef __attribute__((ext_vector_type(8))) short short8;
typedef __attribute__((ext_vector_type(4))) float f32x4;
typedef __attribute__((ext_vector_type(4))) ushort u16x4;

#define GLD16(g, l) __builtin_amdgcn_global_load_lds(                      \
    (const __attribute__((address_space(1))) void*)(g),                    \
    (__attribute__((address_space(3))) void*)(l), 16, 0, 0)

__device__ __forceinline__ float bf2f(ushort u) {
  union { uint i; float f; } c; c.i = (uint)u << 16; return c.f;
}
__device__ __forceinline__ ushort f2bf(float f) {
  __hip_bfloat16 h = __float2bfloat16(f); return *(ushort*)&h;
}

// ---------------------------------------------------------------- kernel A1
// blocks 0..4095: transpose/split per (batch, 32-ch chunk) -> tokb hi rows
// (linear [m][256] bf16) + lobuf lo image (6144 B per (b,ch), pre-swizzled).
// blocks 4096..4863: weight pack (wq|wk|wv -> bf16 wcat, biases -> bcat).
__global__ __launch_bounds__(256) void split_kernel(
    const float* __restrict__ x, ushort* __restrict__ tokb,
    char* __restrict__ lobuf,
    const float* __restrict__ wq, const float* __restrict__ bq,
    const float* __restrict__ wk, const float* __restrict__ bk,
    const float* __restrict__ wv, const float* __restrict__ bv,
    ushort* __restrict__ wcat, float* __restrict__ bcat) {
  __shared__ __align__(16) float raw[32 * 81];   // 10368 B
  const int bid = blockIdx.x;
  const int tid = threadIdx.x;
  if (bid >= 4096) {             // ---- weight pack path
    const int j = bid - 4096, c = tid;
    const int sel = j >> 8, jr = j & 255;
    const float* W  = sel == 0 ? wq : (sel == 1 ? wk : wv);
    const float* Bb = sel == 0 ? bq : (sel == 1 ? bk : bv);
    wcat[(size_t)j * 256 + c] = f2bf(W[jr * 256 + c]);
    if (c == 0) bcat[j] = Bb[jr];
    return;
  }
  const int b = bid >> 3, ch = bid & 7;
  const float* src = x + (size_t)b * (C_ * N_) + ch * 32 * N_;
#pragma unroll
  for (int it = 0; it < 3; ++it) {
    int e4 = tid + it * 256;
    if (e4 < 648) *(f32x4*)&raw[e4 * 4] = *(const f32x4*)&src[e4 * 4];
  }
  char* dst = lobuf + (size_t)bid * 6144;
  __syncthreads();
#pragma unroll
  for (int it = 0; it < 6; ++it) {
    int p = tid + it * 256;
    if (p < 1296) {
      int n = p >> 4, q = p & 15;
      float v0 = raw[(2 * q) * N_ + n];
      float v1 = raw[(2 * q + 1) * N_ + n];
      __hip_bfloat16 h0 = __float2bfloat16(v0);
      __hip_bfloat16 h1 = __float2bfloat16(v1);
      float r0 = v0 - __bfloat162float(h0);
      float r1 = v1 - __bfloat162float(h1);
      __hip_bfloat16 g0 = __float2bfloat16(r0);
      __hip_bfloat16 g1 = __float2bfloat16(r1);
      uint hp = (uint)(*(ushort*)&h0) | ((uint)(*(ushort*)&h1) << 16);
      uint lp = (uint)(*(ushort*)&g0) | ((uint)(*(ushort*)&g1) << 16);
      int off = (((q >> 2) << 4) ^ (((n >> 1) & 3) << 4)) + ((q & 3) << 2);
      *(uint*)(dst + n * 64 + off) = lp;
      *(uint*)&tokb[((size_t)(b * N_ + n)) * 256 + ch * 32 + 2 * q] = hp;
    }
  }
}

// ---------------------------------------------------------------- kernel A2
// Per batch, 768 threads (12 waves; was 4 -> 8 waves/CU, now 24 waves/CU).
// Wave (wr=w>>1, wc=w&1) owns a 16-row x 48-col slab of G: acc[3].
// Staging: exactly ONE GLD16 per thread per chunk (idx = tid, same address
// math as r13 -> bit-identical LDS image); double-buffer wait = vmcnt(1).
// Per-fragment MFMA term/chunk order unchanged -> G, diag, selection
// BIT-IDENTICAL to r13 (absmax must stay exactly 0.1171875).
__global__ __launch_bounds__(768) void knn_kernel(
    const ushort* __restrict__ tokb, const char* __restrict__ lobuf,
    int* __restrict__ knn_idx) {
  __shared__ __align__(16) char smem[31488];     // bufs 2x(HI 6144|LO 6144)
  __shared__ float sqv[96];
  const int b = blockIdx.x;
  const int tid = threadIdx.x;
  const int w = tid >> 6, lane = tid & 63;
  const int wr = w >> 1, wc = w & 1;              // 16-row x 48-col slab
  const int l15 = lane & 15;
  const int g16 = lane >> 4;                      // 16B k-group 0..3

  const char* tb = (const char*)(tokb + (size_t)b * N_ * 256);  // 81 x 512B
  const char* lb = lobuf + (size_t)b * 8 * 6144;

  // prologue: stage chunk 0 -> buf0 (768 slots, 1 per thread)
  {
    int idx = tid;
    if (idx < 384) {
      int n = idx >> 2, gp = idx & 3;
      int g = gp ^ ((n >> 1) & 3);
      GLD16(tb + (size_t)n * 512 + (g << 4), smem + idx * 16);
    } else {
      GLD16(lb + (idx - 384) * 16, smem + idx * 16);
    }
  }

  f32x4 acc[3];
#pragma unroll
  for (int j = 0; j < 3; ++j) acc[j] = {0.f, 0.f, 0.f, 0.f};

#pragma unroll
  for (int ch = 0; ch < 8; ++ch) {
    char* cur = smem + (ch & 1) * 12288;
    char* nxt = smem + ((ch + 1) & 1) * 12288;
    if (ch < 7) {
      int idx = tid;
      if (idx < 384) {
        int n = idx >> 2, gp = idx & 3;
        int g = gp ^ ((n >> 1) & 3);
        GLD16(tb + (size_t)n * 512 + (ch + 1) * 64 + (g << 4),
              nxt + idx * 16);
      } else {
        GLD16(lb + (size_t)(ch + 1) * 6144 + (idx - 384) * 16,
              nxt + idx * 16);
      }
      asm volatile("s_waitcnt vmcnt(1)" ::: "memory");   // cur's load done
    } else {
      asm volatile("s_waitcnt vmcnt(0)" ::: "memory");
    }
    __builtin_amdgcn_s_barrier();
    __builtin_amdgcn_sched_barrier(0);
    // A fragment (one 16-row slab) + 3 B fragments
    const int ra = wr * 16 + l15;
    const int oa = ra * 64 + ((g16 << 4) ^ (((ra >> 1) & 3) << 4));
    short8 ah = *(const short8*)(cur + oa);
    short8 al = *(const short8*)(cur + 6144 + oa);
#pragma unroll
    for (int j = 0; j < 3; ++j) {
      int rb = wc * 48 + j * 16 + l15;
      int ob = rb * 64 + ((g16 << 4) ^ (((rb >> 1) & 3) << 4));
      short8 bh = *(const short8*)(cur + ob);
      short8 bl = *(const short8*)(cur + 6144 + ob);
      acc[j] = __builtin_amdgcn_mfma_f32_16x16x32_bf16(ah, bh, acc[j], 0, 0, 0);
      acc[j] = __builtin_amdgcn_mfma_f32_16x16x32_bf16(ah, bl, acc[j], 0, 0, 0);
      acc[j] = __builtin_amdgcn_mfma_f32_16x16x32_bf16(al, bh, acc[j], 0, 0, 0);
      acc[j] = __builtin_amdgcn_mfma_f32_16x16x32_bf16(al, bl, acc[j], 0, 0, 0);
    }
    __builtin_amdgcn_sched_barrier(0);
    __builtin_amdgcn_s_barrier();   // reads done before next GLD overwrite
  }
  float* G = (float*)smem;
  {
    const int row0 = wr * 16 + ((lane >> 4) << 2);
#pragma unroll
    for (int j = 0; j < 3; ++j) {
      const int col = wc * 48 + j * 16 + l15;
#pragma unroll
      for (int reg = 0; reg < 4; ++reg) {
        const int row = row0 + reg;
        if (row < N_) G[row * 97 + col] = acc[j][reg];
      }
    }
  }
  __syncthreads();
  if (tid < N_) sqv[tid] = G[tid * 97 + tid];   // diag = |token|^2 (4-term)
  __syncthreads();
  if (tid < N_) {
    const int n = tid;
    const float sn = sqv[n];
    const float* grow = &G[n * 97];
    float bd[KNN]; int bi[KNN];
#pragma unroll
    for (int k = 0; k < KNN; ++k) { bd[k] = 3.4e38f; bi[k] = 0; }
    for (int m = 0; m < N_; ++m) {
      float d2 = sn + sqv[m] - 2.f * grow[m];
      float wv = bd[0]; int wi = 0;
#pragma unroll
      for (int k = 1; k < KNN; ++k) {
        bool g_ = bd[k] > wv;
        wv = g_ ? bd[k] : wv;
        wi = g_ ? k : wi;
      }
      bool repl = d2 < wv;
#pragma unroll
      for (int k = 0; k < KNN; ++k) {
        bool here = repl & (wi == k);
        bd[k] = here ? d2 : bd[k];
        bi[k] = here ? m : bi[k];
      }
    }
#pragma unroll
    for (int k = 0; k < KNN; ++k)
      knn_idx[((size_t)b * N_ + n) * KNN + k] = bi[k];
  }
}

// ---------------------------------------------------------------- kernel B
// bf16 MFMA GEMM: qkvb[M][768] = tok[M][256] @ wcat^T + bcat (bf16 out).
// XCD-chunked, jt-inner 1D grid (A-tile L2 reuse, verified r12).
__global__ __launch_bounds__(256) void qkv_mfma_kernel(
    const ushort* __restrict__ tokb, const ushort* __restrict__ wcat,
    const float* __restrict__ bcat, ushort* __restrict__ qkvb) {
  __shared__ ushort At[128 * 64];   // 16 KB, row-major [r][k], swizzled
  __shared__ ushort Bt[128 * 64];   // 16 KB
  const int bid = blockIdx.x;       // grid 1968 = 8 * 41 * 6
  const int xcd = bid & 7, li = bid >> 3;      // li 0..245
  const int mt = xcd * 41 + li / 6;            // m-tile 0..327
  if (mt >= 324) return;                       // 24 pad blocks exit
  const int m0 = mt * 128;
  const int j0 = (li % 6) * 128;
  const int tid = threadIdx.x;
  const int w = tid >> 6, lane = tid & 63;
  const int wr = w >> 1, wc = w & 1;

  const char* pA[4]; const char* pB[4]; int oL[4];
#pragma unroll
  for (int it = 0; it < 4; ++it) {
    int o = (it * 256 + tid) * 16;
    int r = o >> 7, cp = o & 127;
    int cl = cp ^ ((r & 7) << 4);
    oL[it] = o;
    pA[it] = (const char*)tokb + ((size_t)(m0 + r) * 256) * 2 + cl;
    pB[it] = (const char*)wcat + ((size_t)(j0 + r) * 256) * 2 + cl;
  }

  f32x4 acc[4][4];
#pragma unroll
  for (int i = 0; i < 4; ++i)
#pragma unroll
    for (int j = 0; j < 4; ++j) acc[i][j] = {0.f, 0.f, 0.f, 0.f};

  const int l15 = lane & 15;
  const int sw = (lane & 7) << 4;
  const int kgrp = (lane >> 4) << 4;

  for (int k0 = 0; k0 < 256; k0 += 64) {
    __syncthreads();
#pragma unroll
    for (int it = 0; it < 4; ++it) {
      GLD16(pA[it] + k0 * 2, (char*)At + oL[it]);
      GLD16(pB[it] + k0 * 2, (char*)Bt + oL[it]);
    }
    __syncthreads();
#pragma unroll
    for (int kk = 0; kk < 2; ++kk) {
      const int cb = (kk * 64 + kgrp) ^ sw;
      short8 am[4], bn[4];
#pragma unroll
      for (int i = 0; i < 4; ++i) {
        const int ra = wr * 64 + i * 16 + l15;
        am[i] = *(const short8*)((const char*)At + ra * 128 + cb);
        const int rb = wc * 64 + i * 16 + l15;
        bn[i] = *(const short8*)((const char*)Bt + rb * 128 + cb);
      }
#pragma unroll
      for (int i = 0; i < 4; ++i)
#pragma unroll
        for (int j = 0; j < 4; ++j)
          acc[i][j] = __builtin_amdgcn_mfma_f32_16x16x32_bf16(
              am[i], bn[j], acc[i][j], 0, 0, 0);
    }
  }

  // epilogue -> bf16 qkv
#pragma unroll
  for (int j = 0; j < 4; ++j) {
    const int colj = j0 + wc * 64 + j * 16 + l15;
    const float bs = bcat[colj];
#pragma unroll
    for (int i = 0; i < 4; ++i) {
      const int rowm = m0 + wr * 64 + i * 16 + ((lane >> 4) << 2);
#pragma unroll
      for (int reg = 0; reg < 4; ++reg)
        qkvb[(size_t)(rowm + reg) * 768 + colj] = f2bf(acc[i][j][reg] + bs);
    }
  }
}

// ---------------------------------------------------------------- kernel C
// One WAVE per token, bf16 q/k/v. kidx via ONE lane-parallel load (lane<9)
// + v_readlane broadcast. Writes bf16 output in place into the q-slot.
// (r13 verbatim)
__global__ __launch_bounds__(256) void attn_kernel(
    const ushort* __restrict__ qkvc, const int* __restrict__ knn_idx,
    const float* __restrict__ a, ushort* __restrict__ qkvb) {
  const int nwg = M_ / 4;                    // 10368 = 8 * 1296
  const int bid = blockIdx.x;
  const int swz = (bid & 7) * (nwg / 8) + (bid >> 3);  // XCD-contiguous
  const int w = threadIdx.x >> 6, lane = threadIdx.x & 63;
  const int m = swz * 4 + w;                 // this wave's token
  const int b = m / N_;
  const int bbase = b * N_;

  int nbk_l = 0;
  if (lane < KNN) nbk_l = knn_idx[(size_t)m * KNN + lane];

  const u16x4 qu = *(const u16x4*)&qkvc[(size_t)m * 768 + lane * 4];
  const f32x4 a4 = *(const f32x4*)&a[lane * 4];
  float q4[4];
#pragma unroll
  for (int u = 0; u < 4; ++u) q4[u] = bf2f(qu[u]);

  float sc[KNN];
  int nb[KNN];
#pragma unroll
  for (int k = 0; k < KNN; ++k) {
    const int nbk = __builtin_amdgcn_readlane(nbk_l, k);
    nb[k] = nbk;
    const ushort* krow = qkvc + (size_t)(bbase + nbk) * 768 + 256;
    const u16x4 ku = *(const u16x4*)&krow[lane * 4];
    float p = 0.f;
#pragma unroll
    for (int u = 0; u < 4; ++u) {
      float t = q4[u] + bf2f(ku[u]);
      t = fmaxf(t, 0.2f * t);                // leaky_relu(t, 0.2)
      p = __builtin_fmaf(t, a4[u], p);
    }
    p += __shfl_xor(p, 1, 16);
    p += __shfl_xor(p, 2, 16);
    p += __shfl_xor(p, 4, 16);
    p += __shfl_xor(p, 8, 16);
    sc[k] = p;
  }
  float mx = sc[0];
#pragma unroll
  for (int k = 1; k < KNN; ++k) mx = fmaxf(mx, sc[k]);
  float s = 0.f;
#pragma unroll
  for (int k = 0; k < KNN; ++k) {
    sc[k] = __builtin_amdgcn_exp2f((sc[k] - mx) * 1.44269504f);
    s += sc[k];
  }
  const float inv = __builtin_amdgcn_rcpf(s);
  f32x4 acc = {0.f, 0.f, 0.f, 0.f};
#pragma unroll
  for (int k = 0; k < KNN; ++k) {
    const ushort* vrow = qkvc + (size_t)(bbase + nb[k]) * 768 + 512;
    const u16x4 vu = *(const u16x4*)&vrow[lane * 4];
    const float wk_ = sc[k] * inv;
#pragma unroll
    for (int u = 0; u < 4; ++u)
      acc[u] = __builtin_fmaf(wk_, bf2f(vu[u]), acc[u]);
  }
  u16x4 o;
#pragma unroll
  for (int u = 0; u < 4; ++u) o[u] = f2bf(acc[u]);
  *(u16x4*)&qkvb[(size_t)m * 768 + lane * 4] = o;   // overwrite own q-slot
}

// ---------------------------------------------------------------- kernel D
// Deterministic two-stage BN stats over bf16 q-slots (stride 768).
__global__ __launch_bounds__(256) void bn_partial_kernel(
    const ushort* __restrict__ qkvb, float* __restrict__ ps,
    float* __restrict__ ps2) {
  const int g = blockIdx.x, c = threadIdx.x;
  float s = 0.f, s2 = 0.f;
  for (int r = 0; r < M_ / 256; ++r) {
    float v = bf2f(qkvb[((size_t)g * (M_ / 256) + r) * 768 + c]);
    s += v; s2 += v * v;
  }
  ps[g * 256 + c] = s;
  ps2[g * 256 + c] = s2;
}

__global__ __launch_bounds__(256) void bn_finalize_kernel(
    const float* __restrict__ ps, const float* __restrict__ ps2,
    const float* __restrict__ gamma, const float* __restrict__ beta,
    float* __restrict__ scale, float* __restrict__ shift) {
  const int c = threadIdx.x;
  float s = 0.f, s2 = 0.f;
  for (int g = 0; g < 256; ++g) { s += ps[g * 256 + c]; s2 += ps2[g * 256 + c]; }
  const float mean = s * (1.f / (float)M_);
  const float var = s2 * (1.f / (float)M_) - mean * mean;
  const float rstd = rsqrtf(var + 1e-5f);
  scale[c] = gamma[c] * rstd;
  shift[c] = beta[c] - mean * gamma[c] * rstd;
}

// ---------------------------------------------------------------- kernel E
// y = relu(attn*scale + shift + x), transposed back to [B][C][81] via LDS.
__global__ __launch_bounds__(256) void bn_apply_kernel(
    const ushort* __restrict__ qkvb, const float* __restrict__ x,
    const float* __restrict__ scale, const float* __restrict__ shift,
    float* __restrict__ y) {
  __shared__ float t[N_ * 65];
  const int b = blockIdx.x, tid = threadIdx.x;
  for (int c0 = 0; c0 < 256; c0 += 64) {
    __syncthreads();
    for (int e = tid; e < N_ * 64; e += 256) {
      int n = e >> 6, c = e & 63;
      t[n * 65 + c] = bf2f(qkvb[((size_t)b * N_ + n) * 768 + c0 + c]);
    }
    __syncthreads();
    for (int f = tid; f < 64 * N_; f += 256) {
      int c = f / N_, n = f - c * N_;
      float o = t[n * 65 + c];
      size_t gi = (size_t)b * (C_ * N_) + (size_t)(c0 + c) * N_ + n;
      float bn = o * scale[c0 + c] + shift[c0 + c];
      float v = bn + x[gi];
      y[gi] = v > 0.f ? v : 0.f;
    }
  }
}

// ----------------------------------------------------------------
extern "C" void kernel_launch(void* const* d_in, const int* in_sizes, int n_in,
                              void* d_out, int out_size, void* d_ws,
                              size_t ws_size, hipStream_t stream) {
  const float* x     = (const float*)d_in[0];
  const float* wq    = (const float*)d_in[1];
  const float* bq    = (const float*)d_in[2];
  const float* wk    = (const float*)d_in[3];
  const float* bk    = (const float*)d_in[4];
  const float* wv    = (const float*)d_in[5];
  const float* bv    = (const float*)d_in[6];
  const float* a     = (const float*)d_in[7];
  const float* gamma = (const float*)d_in[8];
  const float* beta  = (const float*)d_in[9];
  float* out = (float*)d_out;

  ushort* qkvb = (ushort*)d_ws;                         // M*768 bf16 (63.7MB)
  char*   lobuf = (char*)qkvb;                          // 25.2 MB alias,
                                                        // consumed pre-qkv
  ushort* tokb = qkvb + (size_t)M_ * 768;               // M*256 bf16
  ushort* wcat = tokb + (size_t)M_ * 256;               // 768*256 bf16
  float*  bcat = (float*)(wcat + 768 * 256);            // 768 f32
  int*    kidx = (int*)(bcat + 768);                    // M*9 int
  float*  ps   = (float*)(kidx + (size_t)M_ * KNN);     // 256*256
  float*  ps2  = ps + 256 * 256;                        // 256*256
  float*  scale = ps2 + 256 * 256;                      // 256
  float*  shift = scale + 256;                          // 256

  split_kernel<<<4096 + 768, 256, 0, stream>>>(
      x, tokb, lobuf, wq, bq, wk, bk, wv, bv, wcat, bcat);
  knn_kernel<<<B_, 768, 0, stream>>>(tokb, lobuf, kidx);
  qkv_mfma_kernel<<<1968, 256, 0, stream>>>(tokb, wcat, bcat, qkvb);
  attn_kernel<<<M_ / 4, 256, 0, stream>>>(qkvb, kidx, a, qkvb);
  bn_partial_kernel<<<256, 256, 0, stream>>>(qkvb, ps, ps2);
  bn_finalize_kernel<<<1, 256, 0, stream>>>(ps, ps2, gamma, beta, scale, shift);
  bn_apply_kernel<<<B_, 256, 0, stream>>>(qkvb, x, scale, shift, out);
}

// Round 16
// 151.143 us; speedup vs baseline: 1.1120x; 1.0529x over previous
//
#include <hip/hip_runtime.h>
#include <hip/hip_bf16.h>

#define B_   512
#define C_   256
#define N_   81                 // tokens per batch (9x9)
#define M_   (B_ * N_)          // 41472
#define KNN  9

typedef __attribute__((ext_vector_type(8))) short short8;
typedef __attribute__((ext_vector_type(4))) float f32x4;
typedef __attribute__((ext_vector_type(4))) ushort u16x4;

#define GLD16(g, l) __builtin_amdgcn_global_load_lds(                      \
    (const __attribute__((address_space(1))) void*)(g),                    \
    (__attribute__((address_space(3))) void*)(l), 16, 0, 0)

__device__ __forceinline__ float bf2f(ushort u) {
  union { uint i; float f; } c; c.i = (uint)u << 16; return c.f;
}
__device__ __forceinline__ ushort f2bf(float f) {
  __hip_bfloat16 h = __float2bfloat16(f); return *(ushort*)&h;
}

// ---------------------------------------------------------------- kernel A1
// blocks 0..4095: transpose/split per (batch, 32-ch chunk) -> tokb hi rows
// (linear [m][256] bf16) + lobuf lo image (6144 B per (b,ch), pre-swizzled).
// blocks 4096..4863: weight pack (wq|wk|wv -> bf16 wcat, biases -> bcat).
__global__ __launch_bounds__(256) void split_kernel(
    const float* __restrict__ x, ushort* __restrict__ tokb,
    char* __restrict__ lobuf,
    const float* __restrict__ wq, const float* __restrict__ bq,
    const float* __restrict__ wk, const float* __restrict__ bk,
    const float* __restrict__ wv, const float* __restrict__ bv,
    ushort* __restrict__ wcat, float* __restrict__ bcat) {
  __shared__ __align__(16) float raw[32 * 81];   // 10368 B
  const int bid = blockIdx.x;
  const int tid = threadIdx.x;
  if (bid >= 4096) {             // ---- weight pack path
    const int j = bid - 4096, c = tid;
    const int sel = j >> 8, jr = j & 255;
    const float* W  = sel == 0 ? wq : (sel == 1 ? wk : wv);
    const float* Bb = sel == 0 ? bq : (sel == 1 ? bk : bv);
    wcat[(size_t)j * 256 + c] = f2bf(W[jr * 256 + c]);
    if (c == 0) bcat[j] = Bb[jr];
    return;
  }
  const int b = bid >> 3, ch = bid & 7;
  const float* src = x + (size_t)b * (C_ * N_) + ch * 32 * N_;
#pragma unroll
  for (int it = 0; it < 3; ++it) {
    int e4 = tid + it * 256;
    if (e4 < 648) *(f32x4*)&raw[e4 * 4] = *(const f32x4*)&src[e4 * 4];
  }
  char* dst = lobuf + (size_t)bid * 6144;
  __syncthreads();
#pragma unroll
  for (int it = 0; it < 6; ++it) {
    int p = tid + it * 256;
    if (p < 1296) {
      int n = p >> 4, q = p & 15;
      float v0 = raw[(2 * q) * N_ + n];
      float v1 = raw[(2 * q + 1) * N_ + n];
      __hip_bfloat16 h0 = __float2bfloat16(v0);
      __hip_bfloat16 h1 = __float2bfloat16(v1);
      float r0 = v0 - __bfloat162float(h0);
      float r1 = v1 - __bfloat162float(h1);
      __hip_bfloat16 g0 = __float2bfloat16(r0);
      __hip_bfloat16 g1 = __float2bfloat16(r1);
      uint hp = (uint)(*(ushort*)&h0) | ((uint)(*(ushort*)&h1) << 16);
      uint lp = (uint)(*(ushort*)&g0) | ((uint)(*(ushort*)&g1) << 16);
      int off = (((q >> 2) << 4) ^ (((n >> 1) & 3) << 4)) + ((q & 3) << 2);
      *(uint*)(dst + n * 64 + off) = lp;
      *(uint*)&tokb[((size_t)(b * N_ + n)) * 256 + ch * 32 + 2 * q] = hp;
    }
  }
}

// ---------------------------------------------------------------- kernel A2
// Per batch, 768 threads (12 waves -> 24 waves/CU). Wave (wr,wc) owns a
// 16-row x 48-col slab of G: acc[3]. One GLD16 per thread per chunk,
// double-buffer wait = vmcnt(1). Bit-identical output (verified r15).
__global__ __launch_bounds__(768) void knn_kernel(
    const ushort* __restrict__ tokb, const char* __restrict__ lobuf,
    int* __restrict__ knn_idx) {
  __shared__ __align__(16) char smem[31488];     // bufs 2x(HI 6144|LO 6144)
  __shared__ float sqv[96];
  const int b = blockIdx.x;
  const int tid = threadIdx.x;
  const int w = tid >> 6, lane = tid & 63;
  const int wr = w >> 1, wc = w & 1;              // 16-row x 48-col slab
  const int l15 = lane & 15;
  const int g16 = lane >> 4;                      // 16B k-group 0..3

  const char* tb = (const char*)(tokb + (size_t)b * N_ * 256);  // 81 x 512B
  const char* lb = lobuf + (size_t)b * 8 * 6144;

  {
    int idx = tid;
    if (idx < 384) {
      int n = idx >> 2, gp = idx & 3;
      int g = gp ^ ((n >> 1) & 3);
      GLD16(tb + (size_t)n * 512 + (g << 4), smem + idx * 16);
    } else {
      GLD16(lb + (idx - 384) * 16, smem + idx * 16);
    }
  }

  f32x4 acc[3];
#pragma unroll
  for (int j = 0; j < 3; ++j) acc[j] = {0.f, 0.f, 0.f, 0.f};

#pragma unroll
  for (int ch = 0; ch < 8; ++ch) {
    char* cur = smem + (ch & 1) * 12288;
    char* nxt = smem + ((ch + 1) & 1) * 12288;
    if (ch < 7) {
      int idx = tid;
      if (idx < 384) {
        int n = idx >> 2, gp = idx & 3;
        int g = gp ^ ((n >> 1) & 3);
        GLD16(tb + (size_t)n * 512 + (ch + 1) * 64 + (g << 4),
              nxt + idx * 16);
      } else {
        GLD16(lb + (size_t)(ch + 1) * 6144 + (idx - 384) * 16,
              nxt + idx * 16);
      }
      asm volatile("s_waitcnt vmcnt(1)" ::: "memory");   // cur's load done
    } else {
      asm volatile("s_waitcnt vmcnt(0)" ::: "memory");
    }
    __builtin_amdgcn_s_barrier();
    __builtin_amdgcn_sched_barrier(0);
    const int ra = wr * 16 + l15;
    const int oa = ra * 64 + ((g16 << 4) ^ (((ra >> 1) & 3) << 4));
    short8 ah = *(const short8*)(cur + oa);
    short8 al = *(const short8*)(cur + 6144 + oa);
#pragma unroll
    for (int j = 0; j < 3; ++j) {
      int rb = wc * 48 + j * 16 + l15;
      int ob = rb * 64 + ((g16 << 4) ^ (((rb >> 1) & 3) << 4));
      short8 bh = *(const short8*)(cur + ob);
      short8 bl = *(const short8*)(cur + 6144 + ob);
      acc[j] = __builtin_amdgcn_mfma_f32_16x16x32_bf16(ah, bh, acc[j], 0, 0, 0);
      acc[j] = __builtin_amdgcn_mfma_f32_16x16x32_bf16(ah, bl, acc[j], 0, 0, 0);
      acc[j] = __builtin_amdgcn_mfma_f32_16x16x32_bf16(al, bh, acc[j], 0, 0, 0);
      acc[j] = __builtin_amdgcn_mfma_f32_16x16x32_bf16(al, bl, acc[j], 0, 0, 0);
    }
    __builtin_amdgcn_sched_barrier(0);
    __builtin_amdgcn_s_barrier();   // reads done before next GLD overwrite
  }
  float* G = (float*)smem;
  {
    const int row0 = wr * 16 + ((lane >> 4) << 2);
#pragma unroll
    for (int j = 0; j < 3; ++j) {
      const int col = wc * 48 + j * 16 + l15;
#pragma unroll
      for (int reg = 0; reg < 4; ++reg) {
        const int row = row0 + reg;
        if (row < N_) G[row * 97 + col] = acc[j][reg];
      }
    }
  }
  __syncthreads();
  if (tid < N_) sqv[tid] = G[tid * 97 + tid];   // diag = |token|^2 (4-term)
  __syncthreads();
  if (tid < N_) {
    const int n = tid;
    const float sn = sqv[n];
    const float* grow = &G[n * 97];
    float bd[KNN]; int bi[KNN];
#pragma unroll
    for (int k = 0; k < KNN; ++k) { bd[k] = 3.4e38f; bi[k] = 0; }
    for (int m = 0; m < N_; ++m) {
      float d2 = sn + sqv[m] - 2.f * grow[m];
      float wv = bd[0]; int wi = 0;
#pragma unroll
      for (int k = 1; k < KNN; ++k) {
        bool g_ = bd[k] > wv;
        wv = g_ ? bd[k] : wv;
        wi = g_ ? k : wi;
      }
      bool repl = d2 < wv;
#pragma unroll
      for (int k = 0; k < KNN; ++k) {
        bool here = repl & (wi == k);
        bd[k] = here ? d2 : bd[k];
        bi[k] = here ? m : bi[k];
      }
    }
#pragma unroll
    for (int k = 0; k < KNN; ++k)
      knn_idx[((size_t)b * N_ + n) * KNN + k] = bi[k];
  }
}

// ---------------------------------------------------------------- kernel B
// bf16 MFMA GEMM: qkvb[M][768] = tok[M][256] @ wcat^T + bcat (bf16 out).
// XCD-chunked, jt-inner 1D grid (A-tile L2 reuse, verified r12).
__global__ __launch_bounds__(256) void qkv_mfma_kernel(
    const ushort* __restrict__ tokb, const ushort* __restrict__ wcat,
    const float* __restrict__ bcat, ushort* __restrict__ qkvb) {
  __shared__ ushort At[128 * 64];   // 16 KB, row-major [r][k], swizzled
  __shared__ ushort Bt[128 * 64];   // 16 KB
  const int bid = blockIdx.x;       // grid 1968 = 8 * 41 * 6
  const int xcd = bid & 7, li = bid >> 3;      // li 0..245
  const int mt = xcd * 41 + li / 6;            // m-tile 0..327
  if (mt >= 324) return;                       // 24 pad blocks exit
  const int m0 = mt * 128;
  const int j0 = (li % 6) * 128;
  const int tid = threadIdx.x;
  const int w = tid >> 6, lane = tid & 63;
  const int wr = w >> 1, wc = w & 1;

  const char* pA[4]; const char* pB[4]; int oL[4];
#pragma unroll
  for (int it = 0; it < 4; ++it) {
    int o = (it * 256 + tid) * 16;
    int r = o >> 7, cp = o & 127;
    int cl = cp ^ ((r & 7) << 4);
    oL[it] = o;
    pA[it] = (const char*)tokb + ((size_t)(m0 + r) * 256) * 2 + cl;
    pB[it] = (const char*)wcat + ((size_t)(j0 + r) * 256) * 2 + cl;
  }

  f32x4 acc[4][4];
#pragma unroll
  for (int i = 0; i < 4; ++i)
#pragma unroll
    for (int j = 0; j < 4; ++j) acc[i][j] = {0.f, 0.f, 0.f, 0.f};

  const int l15 = lane & 15;
  const int sw = (lane & 7) << 4;
  const int kgrp = (lane >> 4) << 4;

  for (int k0 = 0; k0 < 256; k0 += 64) {
    __syncthreads();
#pragma unroll
    for (int it = 0; it < 4; ++it) {
      GLD16(pA[it] + k0 * 2, (char*)At + oL[it]);
      GLD16(pB[it] + k0 * 2, (char*)Bt + oL[it]);
    }
    __syncthreads();
#pragma unroll
    for (int kk = 0; kk < 2; ++kk) {
      const int cb = (kk * 64 + kgrp) ^ sw;
      short8 am[4], bn[4];
#pragma unroll
      for (int i = 0; i < 4; ++i) {
        const int ra = wr * 64 + i * 16 + l15;
        am[i] = *(const short8*)((const char*)At + ra * 128 + cb);
        const int rb = wc * 64 + i * 16 + l15;
        bn[i] = *(const short8*)((const char*)Bt + rb * 128 + cb);
      }
#pragma unroll
      for (int i = 0; i < 4; ++i)
#pragma unroll
        for (int j = 0; j < 4; ++j)
          acc[i][j] = __builtin_amdgcn_mfma_f32_16x16x32_bf16(
              am[i], bn[j], acc[i][j], 0, 0, 0);
    }
  }

  // epilogue -> bf16 qkv
#pragma unroll
  for (int j = 0; j < 4; ++j) {
    const int colj = j0 + wc * 64 + j * 16 + l15;
    const float bs = bcat[colj];
#pragma unroll
    for (int i = 0; i < 4; ++i) {
      const int rowm = m0 + wr * 64 + i * 16 + ((lane >> 4) << 2);
#pragma unroll
      for (int reg = 0; reg < 4; ++reg)
        qkvb[(size_t)(rowm + reg) * 768 + colj] = f2bf(acc[i][j][reg] + bs);
    }
  }
}

// ---------------------------------------------------------------- kernel C
// One WAVE per token, bf16 q/k/v. kidx via one lane-parallel load + readlane
// broadcast. ALL 18 k/v row loads issued up front (v addresses depend only
// on nb, not on scores) so v-data lands under the score/shuffle phase --
// T14 issue-early. Writes bf16 output in place into the q-slot.
__global__ __launch_bounds__(256) void attn_kernel(
    const ushort* __restrict__ qkvc, const int* __restrict__ knn_idx,
    const float* __restrict__ a, ushort* __restrict__ qkvb) {
  const int nwg = M_ / 4;                    // 10368 = 8 * 1296
  const int bid = blockIdx.x;
  const int swz = (bid & 7) * (nwg / 8) + (bid >> 3);  // XCD-contiguous
  const int w = threadIdx.x >> 6, lane = threadIdx.x & 63;
  const int m = swz * 4 + w;                 // this wave's token
  const int b = m / N_;
  const int bbase = b * N_;

  int nbk_l = 0;
  if (lane < KNN) nbk_l = knn_idx[(size_t)m * KNN + lane];

  const u16x4 qu = *(const u16x4*)&qkvc[(size_t)m * 768 + lane * 4];
  const f32x4 a4 = *(const f32x4*)&a[lane * 4];
  float q4[4];
#pragma unroll
  for (int u = 0; u < 4; ++u) q4[u] = bf2f(qu[u]);

  // issue all k and v loads up front (18 outstanding 8B loads)
  u16x4 ku[KNN], vu[KNN];
#pragma unroll
  for (int k = 0; k < KNN; ++k) {
    const int nbk = __builtin_amdgcn_readlane(nbk_l, k);
    const ushort* row = qkvc + (size_t)(bbase + nbk) * 768;
    ku[k] = *(const u16x4*)&row[256 + lane * 4];
    vu[k] = *(const u16x4*)&row[512 + lane * 4];
  }

  float sc[KNN];
#pragma unroll
  for (int k = 0; k < KNN; ++k) {
    float p = 0.f;
#pragma unroll
    for (int u = 0; u < 4; ++u) {
      float t = q4[u] + bf2f(ku[k][u]);
      t = fmaxf(t, 0.2f * t);                // leaky_relu(t, 0.2)
      p = __builtin_fmaf(t, a4[u], p);
    }
    p += __shfl_xor(p, 1, 16);
    p += __shfl_xor(p, 2, 16);
    p += __shfl_xor(p, 4, 16);
    p += __shfl_xor(p, 8, 16);
    sc[k] = p;
  }
  float mx = sc[0];
#pragma unroll
  for (int k = 1; k < KNN; ++k) mx = fmaxf(mx, sc[k]);
  float s = 0.f;
#pragma unroll
  for (int k = 0; k < KNN; ++k) {
    sc[k] = __builtin_amdgcn_exp2f((sc[k] - mx) * 1.44269504f);
    s += sc[k];
  }
  const float inv = __builtin_amdgcn_rcpf(s);
  f32x4 acc = {0.f, 0.f, 0.f, 0.f};
#pragma unroll
  for (int k = 0; k < KNN; ++k) {
    const float wk_ = sc[k] * inv;
#pragma unroll
    for (int u = 0; u < 4; ++u)
      acc[u] = __builtin_fmaf(wk_, bf2f(vu[k][u]), acc[u]);
  }
  u16x4 o;
#pragma unroll
  for (int u = 0; u < 4; ++u) o[u] = f2bf(acc[u]);
  *(u16x4*)&qkvb[(size_t)m * 768 + lane * 4] = o;   // overwrite own q-slot
}

// ---------------------------------------------------------------- kernel D
// Deterministic two-stage BN stats over bf16 q-slots (stride 768).
__global__ __launch_bounds__(256) void bn_partial_kernel(
    const ushort* __restrict__ qkvb, float* __restrict__ ps,
    float* __restrict__ ps2) {
  const int g = blockIdx.x, c = threadIdx.x;
  float s = 0.f, s2 = 0.f;
  for (int r = 0; r < M_ / 256; ++r) {
    float v = bf2f(qkvb[((size_t)g * (M_ / 256) + r) * 768 + c]);
    s += v; s2 += v * v;
  }
  ps[g * 256 + c] = s;
  ps2[g * 256 + c] = s2;
}

// Parallel finalize: one block per channel, fixed LDS tree (deterministic).
__global__ __launch_bounds__(256) void bn_finalize_kernel(
    const float* __restrict__ ps, const float* __restrict__ ps2,
    const float* __restrict__ gamma, const float* __restrict__ beta,
    float* __restrict__ scale, float* __restrict__ shift) {
  __shared__ float red[2][256];
  const int c = blockIdx.x, t = threadIdx.x;
  red[0][t] = ps[t * 256 + c];
  red[1][t] = ps2[t * 256 + c];
  __syncthreads();
#pragma unroll
  for (int off = 128; off > 0; off >>= 1) {
    if (t < off) {
      red[0][t] += red[0][t + off];
      red[1][t] += red[1][t + off];
    }
    __syncthreads();
  }
  if (t == 0) {
    const float mean = red[0][0] * (1.f / (float)M_);
    const float var = red[1][0] * (1.f / (float)M_) - mean * mean;
    const float rstd = rsqrtf(var + 1e-5f);
    scale[c] = gamma[c] * rstd;
    shift[c] = beta[c] - mean * gamma[c] * rstd;
  }
}

// ---------------------------------------------------------------- kernel E
// y = relu(attn*scale + shift + x), transposed back to [B][C][81] via LDS.
__global__ __launch_bounds__(256) void bn_apply_kernel(
    const ushort* __restrict__ qkvb, const float* __restrict__ x,
    const float* __restrict__ scale, const float* __restrict__ shift,
    float* __restrict__ y) {
  __shared__ float t[N_ * 65];
  const int b = blockIdx.x, tid = threadIdx.x;
  for (int c0 = 0; c0 < 256; c0 += 64) {
    __syncthreads();
    for (int e = tid; e < N_ * 64; e += 256) {
      int n = e >> 6, c = e & 63;
      t[n * 65 + c] = bf2f(qkvb[((size_t)b * N_ + n) * 768 + c0 + c]);
    }
    __syncthreads();
    for (int f = tid; f < 64 * N_; f += 256) {
      int c = f / N_, n = f - c * N_;
      float o = t[n * 65 + c];
      size_t gi = (size_t)b * (C_ * N_) + (size_t)(c0 + c) * N_ + n;
      float bn = o * scale[c0 + c] + shift[c0 + c];
      float v = bn + x[gi];
      y[gi] = v > 0.f ? v : 0.f;
    }
  }
}

// ----------------------------------------------------------------
extern "C" void kernel_launch(void* const* d_in, const int* in_sizes, int n_in,
                              void* d_out, int out_size, void* d_ws,
                              size_t ws_size, hipStream_t stream) {
  const float* x     = (const float*)d_in[0];
  const float* wq    = (const float*)d_in[1];
  const float* bq    = (const float*)d_in[2];
  const float* wk    = (const float*)d_in[3];
  const float* bk    = (const float*)d_in[4];
  const float* wv    = (const float*)d_in[5];
  const float* bv    = (const float*)d_in[6];
  const float* a     = (const float*)d_in[7];
  const float* gamma = (const float*)d_in[8];
  const float* beta  = (const float*)d_in[9];
  float* out = (float*)d_out;

  ushort* qkvb = (ushort*)d_ws;                         // M*768 bf16 (63.7MB)
  char*   lobuf = (char*)qkvb;                          // 25.2 MB alias,
                                                        // consumed pre-qkv
  ushort* tokb = qkvb + (size_t)M_ * 768;               // M*256 bf16
  ushort* wcat = tokb + (size_t)M_ * 256;               // 768*256 bf16
  float*  bcat = (float*)(wcat + 768 * 256);            // 768 f32
  int*    kidx = (int*)(bcat + 768);                    // M*9 int
  float*  ps   = (float*)(kidx + (size_t)M_ * KNN);     // 256*256
  float*  ps2  = ps + 256 * 256;                        // 256*256
  float*  scale = ps2 + 256 * 256;                      // 256
  float*  shift = scale + 256;                          // 256

  split_kernel<<<4096 + 768, 256, 0, stream>>>(
      x, tokb, lobuf, wq, bq, wk, bk, wv, bv, wcat, bcat);
  knn_kernel<<<B_, 768, 0, stream>>>(tokb, lobuf, kidx);
  qkv_mfma_kernel<<<1968, 256, 0, stream>>>(tokb, wcat, bcat, qkvb);
  attn_kernel<<<M_ / 4, 256, 0, stream>>>(qkvb, kidx, a, qkvb);
  bn_partial_kernel<<<256, 256, 0, stream>>>(qkvb, ps, ps2);
  bn_finalize_kernel<<<256, 256, 0, stream>>>(ps, ps2, gamma, beta, scale, shift);
  bn_apply_kernel<<<B_, 256, 0, stream>>>(qkvb, x, scale, shift, out);
}

// Round 17
// 141.120 us; speedup vs baseline: 1.1909x; 1.0710x over previous
//
#include <hip/hip_runtime.h>
#include <hip/hip_bf16.h>

#define B_   512
#define C_   256
#define N_   81                 // tokens per batch (9x9)
#define M_   (B_ * N_)          // 41472
#define KNN  9

typedef __attribute__((ext_vector_type(8))) short short8;
typedef __attribute__((ext_vector_type(4))) float f32x4;
typedef __attribute__((ext_vector_type(4))) ushort u16x4;

#define GLD16(g, l) __builtin_amdgcn_global_load_lds(                      \
    (const __attribute__((address_space(1))) void*)(g),                    \
    (__attribute__((address_space(3))) void*)(l), 16, 0, 0)

__device__ __forceinline__ float bf2f(ushort u) {
  union { uint i; float f; } c; c.i = (uint)u << 16; return c.f;
}
__device__ __forceinline__ ushort f2bf(float f) {
  __hip_bfloat16 h = __float2bfloat16(f); return *(ushort*)&h;
}

// ---------------------------------------------------------------- kernel A1
// blocks 0..4095: transpose/split per (batch, 32-ch chunk) -> tokb hi rows
// (linear [m][256] bf16) + lobuf lo image (6144 B per (b,ch), pre-swizzled).
// blocks 4096..4863: weight pack (wq|wk|wv -> bf16 wcat, biases -> bcat).
__global__ __launch_bounds__(256) void split_kernel(
    const float* __restrict__ x, ushort* __restrict__ tokb,
    char* __restrict__ lobuf,
    const float* __restrict__ wq, const float* __restrict__ bq,
    const float* __restrict__ wk, const float* __restrict__ bk,
    const float* __restrict__ wv, const float* __restrict__ bv,
    ushort* __restrict__ wcat, float* __restrict__ bcat) {
  __shared__ __align__(16) float raw[32 * 81];   // 10368 B
  const int bid = blockIdx.x;
  const int tid = threadIdx.x;
  if (bid >= 4096) {             // ---- weight pack path
    const int j = bid - 4096, c = tid;
    const int sel = j >> 8, jr = j & 255;
    const float* W  = sel == 0 ? wq : (sel == 1 ? wk : wv);
    const float* Bb = sel == 0 ? bq : (sel == 1 ? bk : bv);
    wcat[(size_t)j * 256 + c] = f2bf(W[jr * 256 + c]);
    if (c == 0) bcat[j] = Bb[jr];
    return;
  }
  const int b = bid >> 3, ch = bid & 7;
  const float* src = x + (size_t)b * (C_ * N_) + ch * 32 * N_;
#pragma unroll
  for (int it = 0; it < 3; ++it) {
    int e4 = tid + it * 256;
    if (e4 < 648) *(f32x4*)&raw[e4 * 4] = *(const f32x4*)&src[e4 * 4];
  }
  char* dst = lobuf + (size_t)bid * 6144;
  __syncthreads();
#pragma unroll
  for (int it = 0; it < 6; ++it) {
    int p = tid + it * 256;
    if (p < 1296) {
      int n = p >> 4, q = p & 15;
      float v0 = raw[(2 * q) * N_ + n];
      float v1 = raw[(2 * q + 1) * N_ + n];
      __hip_bfloat16 h0 = __float2bfloat16(v0);
      __hip_bfloat16 h1 = __float2bfloat16(v1);
      float r0 = v0 - __bfloat162float(h0);
      float r1 = v1 - __bfloat162float(h1);
      __hip_bfloat16 g0 = __float2bfloat16(r0);
      __hip_bfloat16 g1 = __float2bfloat16(r1);
      uint hp = (uint)(*(ushort*)&h0) | ((uint)(*(ushort*)&h1) << 16);
      uint lp = (uint)(*(ushort*)&g0) | ((uint)(*(ushort*)&g1) << 16);
      int off = (((q >> 2) << 4) ^ (((n >> 1) & 3) << 4)) + ((q & 3) << 2);
      *(uint*)(dst + n * 64 + off) = lp;
      *(uint*)&tokb[((size_t)(b * N_ + n)) * 256 + ch * 32 + 2 * q] = hp;
    }
  }
}

// ---------------------------------------------------------------- kernel AB
// Merged knn + qkv GEMM in ONE launch (they are data-independent; knn is
// latency-bound, gemm BW/MFMA-bound -> co-resident waves overlap, m114).
// bid < 512: r13-verbatim 256-thread knn body (bit-exact verified).
// bid >= 512: r12-verbatim gemm body on bid-512 (512%8==0 keeps XCD chunking).
// One 32 KB LDS arena: knn uses [0,31488)+sqv@31488; gemm At/Bt at 0/16384.
__global__ __launch_bounds__(256) void knn_gemm_kernel(
    const ushort* __restrict__ tokb, const char* __restrict__ lobuf,
    int* __restrict__ knn_idx,
    const ushort* __restrict__ wcat, const float* __restrict__ bcat,
    ushort* __restrict__ qkvb) {
  __shared__ __align__(16) char smem[32768];
  const int bid0 = blockIdx.x;
  const int tid = threadIdx.x;
  const int w = tid >> 6, lane = tid & 63;
  const int l15 = lane & 15;

  if (bid0 < B_) {
    // ================= knn path (r13 verbatim, 256 threads) =============
    float* sqv = (float*)(smem + 31488);          // 384 B, after G overlay
    const int b = bid0;
    const int wr = w >> 1, wc = w & 1;            // 48x48 quadrant of G
    const int g16 = lane >> 4;                    // 16B k-group 0..3

    const char* tb = (const char*)(tokb + (size_t)b * N_ * 256);  // 81x512B
    const char* lb = lobuf + (size_t)b * 8 * 6144;

#pragma unroll
    for (int it = 0; it < 3; ++it) {
      int idx = it * 256 + tid;
      if (idx < 384) {
        int n = idx >> 2, gp = idx & 3;
        int g = gp ^ ((n >> 1) & 3);
        GLD16(tb + (size_t)n * 512 + (g << 4), smem + idx * 16);
      } else {
        GLD16(lb + (idx - 384) * 16, smem + idx * 16);
      }
    }

    f32x4 acc[3][3];
#pragma unroll
    for (int i = 0; i < 3; ++i)
#pragma unroll
      for (int j = 0; j < 3; ++j) acc[i][j] = {0.f, 0.f, 0.f, 0.f};

#pragma unroll
    for (int ch = 0; ch < 8; ++ch) {
      char* cur = smem + (ch & 1) * 12288;
      char* nxt = smem + ((ch + 1) & 1) * 12288;
      if (ch < 7) {
#pragma unroll
        for (int it = 0; it < 3; ++it) {
          int idx = it * 256 + tid;
          if (idx < 384) {
            int n = idx >> 2, gp = idx & 3;
            int g = gp ^ ((n >> 1) & 3);
            GLD16(tb + (size_t)n * 512 + (ch + 1) * 64 + (g << 4),
                  nxt + idx * 16);
          } else {
            GLD16(lb + (size_t)(ch + 1) * 6144 + (idx - 384) * 16,
                  nxt + idx * 16);
          }
        }
        asm volatile("s_waitcnt vmcnt(3)" ::: "memory");   // cur's 3 done
      } else {
        asm volatile("s_waitcnt vmcnt(0)" ::: "memory");
      }
      __builtin_amdgcn_s_barrier();
      __builtin_amdgcn_sched_barrier(0);
      short8 ah[3], al[3], bh[3], bl[3];
#pragma unroll
      for (int i = 0; i < 3; ++i) {
        int ra = wr * 48 + i * 16 + l15;
        int oa = ra * 64 + ((g16 << 4) ^ (((ra >> 1) & 3) << 4));
        ah[i] = *(const short8*)(cur + oa);
        al[i] = *(const short8*)(cur + 6144 + oa);
        int rb = wc * 48 + i * 16 + l15;
        int ob = rb * 64 + ((g16 << 4) ^ (((rb >> 1) & 3) << 4));
        bh[i] = *(const short8*)(cur + ob);
        bl[i] = *(const short8*)(cur + 6144 + ob);
      }
#pragma unroll
      for (int i = 0; i < 3; ++i)
#pragma unroll
        for (int j = 0; j < 3; ++j) {
          acc[i][j] = __builtin_amdgcn_mfma_f32_16x16x32_bf16(
              ah[i], bh[j], acc[i][j], 0, 0, 0);
          acc[i][j] = __builtin_amdgcn_mfma_f32_16x16x32_bf16(
              ah[i], bl[j], acc[i][j], 0, 0, 0);
          acc[i][j] = __builtin_amdgcn_mfma_f32_16x16x32_bf16(
              al[i], bh[j], acc[i][j], 0, 0, 0);
          acc[i][j] = __builtin_amdgcn_mfma_f32_16x16x32_bf16(
              al[i], bl[j], acc[i][j], 0, 0, 0);
        }
      __builtin_amdgcn_sched_barrier(0);
      __builtin_amdgcn_s_barrier();   // reads done before next GLD overwrite
    }
    float* G = (float*)smem;
#pragma unroll
    for (int i = 0; i < 3; ++i) {
      const int row0 = wr * 48 + i * 16 + ((lane >> 4) << 2);
#pragma unroll
      for (int j = 0; j < 3; ++j) {
        const int col = wc * 48 + j * 16 + l15;
#pragma unroll
        for (int reg = 0; reg < 4; ++reg) {
          const int row = row0 + reg;
          if (row < N_) G[row * 97 + col] = acc[i][j][reg];
        }
      }
    }
    __syncthreads();
    if (tid < N_) sqv[tid] = G[tid * 97 + tid];   // diag (4-term)
    __syncthreads();
    if (tid < N_) {
      const int n = tid;
      const float sn = sqv[n];
      const float* grow = &G[n * 97];
      float bd[KNN]; int bi[KNN];
#pragma unroll
      for (int k = 0; k < KNN; ++k) { bd[k] = 3.4e38f; bi[k] = 0; }
      for (int m = 0; m < N_; ++m) {
        float d2 = sn + sqv[m] - 2.f * grow[m];
        float wv = bd[0]; int wi = 0;
#pragma unroll
        for (int k = 1; k < KNN; ++k) {
          bool g_ = bd[k] > wv;
          wv = g_ ? bd[k] : wv;
          wi = g_ ? k : wi;
        }
        bool repl = d2 < wv;
#pragma unroll
        for (int k = 0; k < KNN; ++k) {
          bool here = repl & (wi == k);
          bd[k] = here ? d2 : bd[k];
          bi[k] = here ? m : bi[k];
        }
      }
#pragma unroll
      for (int k = 0; k < KNN; ++k)
        knn_idx[((size_t)b * N_ + n) * KNN + k] = bi[k];
    }
    return;
  }

  // ================= gemm path (r12 verbatim, bid-512) ==================
  ushort* At = (ushort*)smem;            // 16 KB
  ushort* Bt = (ushort*)(smem + 16384);  // 16 KB
  const int bid = bid0 - B_;             // 0..1967 = 8 * 41 * 6
  const int xcd = bid & 7, li = bid >> 3;      // li 0..245
  const int mt = xcd * 41 + li / 6;            // m-tile 0..327
  if (mt >= 324) return;                       // 24 pad blocks exit
  const int m0 = mt * 128;
  const int j0 = (li % 6) * 128;
  const int wr = w >> 1, wc = w & 1;

  const char* pA[4]; const char* pB[4]; int oL[4];
#pragma unroll
  for (int it = 0; it < 4; ++it) {
    int o = (it * 256 + tid) * 16;
    int r = o >> 7, cp = o & 127;
    int cl = cp ^ ((r & 7) << 4);
    oL[it] = o;
    pA[it] = (const char*)tokb + ((size_t)(m0 + r) * 256) * 2 + cl;
    pB[it] = (const char*)wcat + ((size_t)(j0 + r) * 256) * 2 + cl;
  }

  f32x4 acc[4][4];
#pragma unroll
  for (int i = 0; i < 4; ++i)
#pragma unroll
    for (int j = 0; j < 4; ++j) acc[i][j] = {0.f, 0.f, 0.f, 0.f};

  const int sw = (lane & 7) << 4;
  const int kgrp = (lane >> 4) << 4;

  for (int k0 = 0; k0 < 256; k0 += 64) {
    __syncthreads();
#pragma unroll
    for (int it = 0; it < 4; ++it) {
      GLD16(pA[it] + k0 * 2, (char*)At + oL[it]);
      GLD16(pB[it] + k0 * 2, (char*)Bt + oL[it]);
    }
    __syncthreads();
#pragma unroll
    for (int kk = 0; kk < 2; ++kk) {
      const int cb = (kk * 64 + kgrp) ^ sw;
      short8 am[4], bn[4];
#pragma unroll
      for (int i = 0; i < 4; ++i) {
        const int ra = wr * 64 + i * 16 + l15;
        am[i] = *(const short8*)((const char*)At + ra * 128 + cb);
        const int rb = wc * 64 + i * 16 + l15;
        bn[i] = *(const short8*)((const char*)Bt + rb * 128 + cb);
      }
#pragma unroll
      for (int i = 0; i < 4; ++i)
#pragma unroll
        for (int j = 0; j < 4; ++j)
          acc[i][j] = __builtin_amdgcn_mfma_f32_16x16x32_bf16(
              am[i], bn[j], acc[i][j], 0, 0, 0);
    }
  }

  // epilogue -> bf16 qkv
#pragma unroll
  for (int j = 0; j < 4; ++j) {
    const int colj = j0 + wc * 64 + j * 16 + l15;
    const float bs = bcat[colj];
#pragma unroll
    for (int i = 0; i < 4; ++i) {
      const int rowm = m0 + wr * 64 + i * 16 + ((lane >> 4) << 2);
#pragma unroll
      for (int reg = 0; reg < 4; ++reg)
        qkvb[(size_t)(rowm + reg) * 768 + colj] = f2bf(acc[i][j][reg] + bs);
    }
  }
}

// ---------------------------------------------------------------- kernel C
// One WAVE per token, bf16 q/k/v. kidx via one lane-parallel load + readlane
// broadcast; all 18 k/v loads issued up front (T14 issue-early, verified
// r16). Writes bf16 output in place into the q-slot.
__global__ __launch_bounds__(256) void attn_kernel(
    const ushort* __restrict__ qkvc, const int* __restrict__ knn_idx,
    const float* __restrict__ a, ushort* __restrict__ qkvb) {
  const int nwg = M_ / 4;                    // 10368 = 8 * 1296
  const int bid = blockIdx.x;
  const int swz = (bid & 7) * (nwg / 8) + (bid >> 3);  // XCD-contiguous
  const int w = threadIdx.x >> 6, lane = threadIdx.x & 63;
  const int m = swz * 4 + w;                 // this wave's token
  const int b = m / N_;
  const int bbase = b * N_;

  int nbk_l = 0;
  if (lane < KNN) nbk_l = knn_idx[(size_t)m * KNN + lane];

  const u16x4 qu = *(const u16x4*)&qkvc[(size_t)m * 768 + lane * 4];
  const f32x4 a4 = *(const f32x4*)&a[lane * 4];
  float q4[4];
#pragma unroll
  for (int u = 0; u < 4; ++u) q4[u] = bf2f(qu[u]);

  u16x4 ku[KNN], vu[KNN];
#pragma unroll
  for (int k = 0; k < KNN; ++k) {
    const int nbk = __builtin_amdgcn_readlane(nbk_l, k);
    const ushort* row = qkvc + (size_t)(bbase + nbk) * 768;
    ku[k] = *(const u16x4*)&row[256 + lane * 4];
    vu[k] = *(const u16x4*)&row[512 + lane * 4];
  }

  float sc[KNN];
#pragma unroll
  for (int k = 0; k < KNN; ++k) {
    float p = 0.f;
#pragma unroll
    for (int u = 0; u < 4; ++u) {
      float t = q4[u] + bf2f(ku[k][u]);
      t = fmaxf(t, 0.2f * t);                // leaky_relu(t, 0.2)
      p = __builtin_fmaf(t, a4[u], p);
    }
    p += __shfl_xor(p, 1, 16);
    p += __shfl_xor(p, 2, 16);
    p += __shfl_xor(p, 4, 16);
    p += __shfl_xor(p, 8, 16);
    sc[k] = p;
  }
  float mx = sc[0];
#pragma unroll
  for (int k = 1; k < KNN; ++k) mx = fmaxf(mx, sc[k]);
  float s = 0.f;
#pragma unroll
  for (int k = 0; k < KNN; ++k) {
    sc[k] = __builtin_amdgcn_exp2f((sc[k] - mx) * 1.44269504f);
    s += sc[k];
  }
  const float inv = __builtin_amdgcn_rcpf(s);
  f32x4 acc = {0.f, 0.f, 0.f, 0.f};
#pragma unroll
  for (int k = 0; k < KNN; ++k) {
    const float wk_ = sc[k] * inv;
#pragma unroll
    for (int u = 0; u < 4; ++u)
      acc[u] = __builtin_fmaf(wk_, bf2f(vu[k][u]), acc[u]);
  }
  u16x4 o;
#pragma unroll
  for (int u = 0; u < 4; ++u) o[u] = f2bf(acc[u]);
  *(u16x4*)&qkvb[(size_t)m * 768 + lane * 4] = o;   // overwrite own q-slot
}

// ---------------------------------------------------------------- kernel D
// Deterministic two-stage BN stats over bf16 q-slots (stride 768).
__global__ __launch_bounds__(256) void bn_partial_kernel(
    const ushort* __restrict__ qkvb, float* __restrict__ ps,
    float* __restrict__ ps2) {
  const int g = blockIdx.x, c = threadIdx.x;
  float s = 0.f, s2 = 0.f;
  for (int r = 0; r < M_ / 256; ++r) {
    float v = bf2f(qkvb[((size_t)g * (M_ / 256) + r) * 768 + c]);
    s += v; s2 += v * v;
  }
  ps[g * 256 + c] = s;
  ps2[g * 256 + c] = s2;
}

// Parallel finalize: one block per channel, fixed LDS tree (deterministic).
__global__ __launch_bounds__(256) void bn_finalize_kernel(
    const float* __restrict__ ps, const float* __restrict__ ps2,
    const float* __restrict__ gamma, const float* __restrict__ beta,
    float* __restrict__ scale, float* __restrict__ shift) {
  __shared__ float red[2][256];
  const int c = blockIdx.x, t = threadIdx.x;
  red[0][t] = ps[t * 256 + c];
  red[1][t] = ps2[t * 256 + c];
  __syncthreads();
#pragma unroll
  for (int off = 128; off > 0; off >>= 1) {
    if (t < off) {
      red[0][t] += red[0][t + off];
      red[1][t] += red[1][t + off];
    }
    __syncthreads();
  }
  if (t == 0) {
    const float mean = red[0][0] * (1.f / (float)M_);
    const float var = red[1][0] * (1.f / (float)M_) - mean * mean;
    const float rstd = rsqrtf(var + 1e-5f);
    scale[c] = gamma[c] * rstd;
    shift[c] = beta[c] - mean * gamma[c] * rstd;
  }
}

// ---------------------------------------------------------------- kernel E
// y = relu(attn*scale + shift + x), transposed back to [B][C][81] via LDS.
__global__ __launch_bounds__(256) void bn_apply_kernel(
    const ushort* __restrict__ qkvb, const float* __restrict__ x,
    const float* __restrict__ scale, const float* __restrict__ shift,
    float* __restrict__ y) {
  __shared__ float t[N_ * 65];
  const int b = blockIdx.x, tid = threadIdx.x;
  for (int c0 = 0; c0 < 256; c0 += 64) {
    __syncthreads();
    for (int e = tid; e < N_ * 64; e += 256) {
      int n = e >> 6, c = e & 63;
      t[n * 65 + c] = bf2f(qkvb[((size_t)b * N_ + n) * 768 + c0 + c]);
    }
    __syncthreads();
    for (int f = tid; f < 64 * N_; f += 256) {
      int c = f / N_, n = f - c * N_;
      float o = t[n * 65 + c];
      size_t gi = (size_t)b * (C_ * N_) + (size_t)(c0 + c) * N_ + n;
      float bn = o * scale[c0 + c] + shift[c0 + c];
      float v = bn + x[gi];
      y[gi] = v > 0.f ? v : 0.f;
    }
  }
}

// ----------------------------------------------------------------
extern "C" void kernel_launch(void* const* d_in, const int* in_sizes, int n_in,
                              void* d_out, int out_size, void* d_ws,
                              size_t ws_size, hipStream_t stream) {
  const float* x     = (const float*)d_in[0];
  const float* wq    = (const float*)d_in[1];
  const float* bq    = (const float*)d_in[2];
  const float* wk    = (const float*)d_in[3];
  const float* bk    = (const float*)d_in[4];
  const float* wv    = (const float*)d_in[5];
  const float* bv    = (const float*)d_in[6];
  const float* a     = (const float*)d_in[7];
  const float* gamma = (const float*)d_in[8];
  const float* beta  = (const float*)d_in[9];
  float* out = (float*)d_out;

  ushort* qkvb = (ushort*)d_ws;                         // M*768 bf16 (63.7MB)
  char*   lobuf = (char*)qkvb;                          // 25.2 MB alias --
  // NOTE: lobuf is read by knn blocks while gemm blocks write qkvb in the
  // same launch. Overlap check: lobuf spans [0, 25.2MB) of qkvb's 63.7MB;
  // gemm writes qkvb rows in the same region! Must NOT alias. Move lobuf
  // past qkvb instead (workspace is large enough).
  ushort* tokb = qkvb + (size_t)M_ * 768;               // M*256 bf16
  ushort* wcat = tokb + (size_t)M_ * 256;               // 768*256 bf16
  float*  bcat = (float*)(wcat + 768 * 256);            // 768 f32
  int*    kidx = (int*)(bcat + 768);                    // M*9 int
  float*  ps   = (float*)(kidx + (size_t)M_ * KNN);     // 256*256
  float*  ps2  = ps + 256 * 256;                        // 256*256
  float*  scale = ps2 + 256 * 256;                      // 256
  float*  shift = scale + 256;                          // 256
  char*   lobuf2 = (char*)(shift + 256);                // 25.2 MB, no alias

  split_kernel<<<4096 + 768, 256, 0, stream>>>(
      x, tokb, lobuf2, wq, bq, wk, bk, wv, bv, wcat, bcat);
  knn_gemm_kernel<<<B_ + 1968, 256, 0, stream>>>(
      tokb, lobuf2, kidx, wcat, bcat, qkvb);
  attn_kernel<<<M_ / 4, 256, 0, stream>>>(qkvb, kidx, a, qkvb);
  bn_partial_kernel<<<256, 256, 0, stream>>>(qkvb, ps, ps2);
  bn_finalize_kernel<<<256, 256, 0, stream>>>(ps, ps2, gamma, beta, scale, shift);
  bn_apply_kernel<<<B_, 256, 0, stream>>>(qkvb, x, scale, shift, out);
}